// Round 6
// baseline (12227.534 us; speedup 1.0000x reference)
//
#include <hip/hip_runtime.h>

#define B_ 8
#define P_ 8192
#define M_ 2048
#define K_ 32
#define CIN_ 64
#define C3_ 128
#define BM_ (B_*M_)
#define NTOT_f 524288.0f
#define BN_EPS_ 1e-5f

// workspace layout (in floats): idx (ints) | y3max | y3min | stats
#define WS_Y3MAX (BM_*K_)
#define WS_Y3MIN (WS_Y3MAX + BM_*C3_)
#define WS_STATS (WS_Y3MIN + BM_*C3_)        // 512 floats

__device__ inline int center_index(int m) {
  const double step = (double)(P_ - 1) / (double)(M_ - 1);
  return (m == M_ - 1) ? (P_ - 1) : (int)((double)m * step);
}

// strict (non-contracted) f32 sum of squares in np association: (x2+y2)+z2
__device__ inline float sq3(float a, float b, float c) {
  return __fadd_rn(__fadd_rn(__fmul_rn(a, a), __fmul_rn(b, b)), __fmul_rn(c, c));
}

// ---------------- KNN: brute-force exact top-K, GOLDEN-f32 d2 -------------
// d2 = (ccs + pp) - 2*dot, with dot = fma(c2,p2, fma(c1,p1, c0*p0)) (BLAS/XLA
// style FMA chain), squares/sums/final combine strict _rn. Ties: lowest index.
__global__ __launch_bounds__(256) void k_knn_bf(const float* __restrict__ xyz,
                                                float* __restrict__ centers_out,
                                                int* __restrict__ knn_idx) {
  __shared__ float wmin[4];
  __shared__ int   widx[4];
  __shared__ int   seli_s;
  const int cid = blockIdx.x;
  const int b = cid >> 11;
  const int m = cid & (M_ - 1);
  const int t = threadIdx.x, lane = t & 63, w = t >> 6;
  const float* xyzb = xyz + (size_t)b * P_ * 3;
  const int ci = center_index(m);
  const float cx = xyzb[ci * 3 + 0];
  const float cy = xyzb[ci * 3 + 1];
  const float cz = xyzb[ci * 3 + 2];
  const float ccs = sq3(cx, cy, cz);
  if (t < 3) centers_out[(size_t)cid * 3 + t] = xyzb[ci * 3 + t];

  float d2r[32];
  #pragma unroll
  for (int i = 0; i < 32; i++) {
    int p = t + 256 * i;
    float px = xyzb[p * 3 + 0];
    float py = xyzb[p * 3 + 1];
    float pz = xyzb[p * 3 + 2];
    float pp = sq3(px, py, pz);
    float dot = __fmul_rn(cx, px);
    dot = __builtin_fmaf(cy, py, dot);
    dot = __builtin_fmaf(cz, pz, dot);
    d2r[i] = __fsub_rn(__fadd_rn(ccs, pp), __fmul_rn(2.0f, dot));
  }

  unsigned used = 0u;
  for (int k = 0; k < K_; k++) {
    float bv = __builtin_inff();
    int bi = 0x7fffffff;
    #pragma unroll
    for (int i = 0; i < 32; i++) {
      bool ok = ((used >> i) & 1u) == 0u;
      float v = d2r[i];
      int ix = t + 256 * i;
      bool better = ok && ((v < bv) || (v == bv && ix < bi));
      if (better) { bv = v; bi = ix; }
    }
    for (int d = 1; d < 64; d <<= 1) {
      float ov = __shfl_xor(bv, d);
      int oi = __shfl_xor(bi, d);
      if ((ov < bv) || (ov == bv && oi < bi)) { bv = ov; bi = oi; }
    }
    if (lane == 0) { wmin[w] = bv; widx[w] = bi; }
    __syncthreads();
    if (t == 0) {
      float fv = wmin[0]; int fi = widx[0];
      #pragma unroll
      for (int q = 1; q < 4; q++) {
        if ((wmin[q] < fv) || (wmin[q] == fv && widx[q] < fi)) { fv = wmin[q]; fi = widx[q]; }
      }
      seli_s = fi;
      knn_idx[(size_t)cid * K_ + k] = fi;
    }
    __syncthreads();
    int fi = seli_s;
    if ((fi & 255) == t) used |= 1u << (fi >> 8);
  }
}

// ------------- naive gather: x[67] for this (cid, k) in registers ---------
__device__ inline void naive_gather(const float* __restrict__ xyz,
                                    const float* __restrict__ feats,
                                    const int* __restrict__ knn,
                                    int cid, int k, float* x) {
  const int b = cid >> 11;
  const int m = cid & (M_ - 1);
  const int ci = center_index(m);
  const float* xyzb = xyz + (size_t)b * P_ * 3;
  const int p = knn[(size_t)cid * K_ + k];
  x[0] = xyzb[p * 3 + 0] - xyzb[ci * 3 + 0];
  x[1] = xyzb[p * 3 + 1] - xyzb[ci * 3 + 1];
  x[2] = xyzb[p * 3 + 2] - xyzb[ci * 3 + 2];
  const float* fb = feats + (size_t)b * CIN_ * P_ + p;
  for (int c = 0; c < CIN_; c++) x[3 + c] = fb[(size_t)c * P_];
}

// ---------------- pass 1: y1 stats ----------------
__global__ __launch_bounds__(256) void n_stats1(const float* __restrict__ xyz,
                                                const float* __restrict__ feats,
                                                const int* __restrict__ knn,
                                                const float* __restrict__ W1,
                                                const float* __restrict__ b1,
                                                float* __restrict__ stats) {
  const int gid = blockIdx.x * 256 + threadIdx.x;
  const int cid = gid >> 5, k = gid & 31, lane = threadIdx.x & 63;
  float x[67];
  naive_gather(xyz, feats, knn, cid, k, x);
  for (int o = 0; o < 64; o++) {
    const float* wr = W1 + o * 67;
    float y = b1[o];
    for (int c = 0; c < 67; c++) y = fmaf(x[c], wr[c], y);
    float s = y, q = y * y;
    for (int d = 1; d < 64; d <<= 1) { s += __shfl_xor(s, d); q += __shfl_xor(q, d); }
    if (lane == 0) { atomicAdd(&stats[o], s); atomicAdd(&stats[64 + o], q); }
  }
}

// ---------------- pass 2: recompute y1, bn1+relu, y2 stats ----------------
__global__ __launch_bounds__(256) void n_stats2(const float* __restrict__ xyz,
                                                const float* __restrict__ feats,
                                                const int* __restrict__ knn,
                                                const float* __restrict__ W1,
                                                const float* __restrict__ b1,
                                                const float* __restrict__ g1,
                                                const float* __restrict__ be1,
                                                const float* __restrict__ W2,
                                                const float* __restrict__ b2,
                                                float* __restrict__ stats) {
  const int gid = blockIdx.x * 256 + threadIdx.x;
  const int cid = gid >> 5, k = gid & 31, lane = threadIdx.x & 63;
  float x[67];
  naive_gather(xyz, feats, knn, cid, k, x);
  float h[64];
  for (int o = 0; o < 64; o++) {
    const float* wr = W1 + o * 67;
    float y = b1[o];
    for (int c = 0; c < 67; c++) y = fmaf(x[c], wr[c], y);
    float mean = stats[o] * (1.0f / NTOT_f);
    float var = stats[64 + o] * (1.0f / NTOT_f) - mean * mean;
    float rs = rsqrtf(var + BN_EPS_);
    h[o] = fmaxf((y - mean) * rs * g1[o] + be1[o], 0.0f);
  }
  for (int o = 0; o < 64; o++) {
    const float* wr = W2 + o * 64;
    float y = b2[o];
    for (int c = 0; c < 64; c++) y = fmaf(h[c], wr[c], y);
    float s = y, q = y * y;
    for (int d = 1; d < 64; d <<= 1) { s += __shfl_xor(s, d); q += __shfl_xor(q, d); }
    if (lane == 0) { atomicAdd(&stats[128 + o], s); atomicAdd(&stats[192 + o], q); }
  }
}

// ---------------- pass 3: full recompute, y3 stats + max/min over k -------
__global__ __launch_bounds__(256) void n_stats3(const float* __restrict__ xyz,
                                                const float* __restrict__ feats,
                                                const int* __restrict__ knn,
                                                const float* __restrict__ W1,
                                                const float* __restrict__ b1,
                                                const float* __restrict__ g1,
                                                const float* __restrict__ be1,
                                                const float* __restrict__ W2,
                                                const float* __restrict__ b2,
                                                const float* __restrict__ g2,
                                                const float* __restrict__ be2,
                                                const float* __restrict__ W3,
                                                const float* __restrict__ b3,
                                                float* __restrict__ stats,
                                                float* __restrict__ y3max,
                                                float* __restrict__ y3min) {
  const int gid = blockIdx.x * 256 + threadIdx.x;
  const int cid = gid >> 5, k = gid & 31, lane = threadIdx.x & 63;
  float x[67];
  naive_gather(xyz, feats, knn, cid, k, x);
  float h[64];
  for (int o = 0; o < 64; o++) {
    const float* wr = W1 + o * 67;
    float y = b1[o];
    for (int c = 0; c < 67; c++) y = fmaf(x[c], wr[c], y);
    float mean = stats[o] * (1.0f / NTOT_f);
    float var = stats[64 + o] * (1.0f / NTOT_f) - mean * mean;
    float rs = rsqrtf(var + BN_EPS_);
    h[o] = fmaxf((y - mean) * rs * g1[o] + be1[o], 0.0f);
  }
  float h2[64];
  for (int o = 0; o < 64; o++) {
    const float* wr = W2 + o * 64;
    float y = b2[o];
    for (int c = 0; c < 64; c++) y = fmaf(h[c], wr[c], y);
    float mean = stats[128 + o] * (1.0f / NTOT_f);
    float var = stats[192 + o] * (1.0f / NTOT_f) - mean * mean;
    float rs = rsqrtf(var + BN_EPS_);
    h2[o] = fmaxf((y - mean) * rs * g2[o] + be2[o], 0.0f);
  }
  for (int o = 0; o < 128; o++) {
    const float* wr = W3 + o * 64;
    float y = b3[o];
    for (int c = 0; c < 64; c++) y = fmaf(h2[c], wr[c], y);
    float s = y, q = y * y;
    for (int d = 1; d < 64; d <<= 1) { s += __shfl_xor(s, d); q += __shfl_xor(q, d); }
    if (lane == 0) { atomicAdd(&stats[256 + o], s); atomicAdd(&stats[384 + o], q); }
    float mx = y, mn = y;
    for (int d = 1; d < 32; d <<= 1) {
      mx = fmaxf(mx, __shfl_xor(mx, d));
      mn = fminf(mn, __shfl_xor(mn, d));
    }
    if (k == 0) {
      y3max[(size_t)cid * C3_ + o] = mx;
      y3min[(size_t)cid * C3_ + o] = mn;
    }
  }
}

// ---------------- final output ----------------
__global__ __launch_bounds__(256) void k_out(const float* __restrict__ y3max,
                                             const float* __restrict__ y3min,
                                             const float* __restrict__ stats,
                                             const float* __restrict__ g3,
                                             const float* __restrict__ be3,
                                             float* __restrict__ outp) {
  int gid = blockIdx.x * 256 + threadIdx.x;
  int m = gid & (M_ - 1);
  int o = (gid >> 11) & 127;
  int b = gid >> 18;
  float mean = stats[256 + o] * (1.0f / NTOT_f);
  float var = stats[384 + o] * (1.0f / NTOT_f) - mean * mean;
  float rs = rsqrtf(var + BN_EPS_);
  float scale = rs * g3[o];
  size_t src = ((size_t)(b * M_ + m)) * C3_ + o;
  float v = (scale >= 0.0f) ? y3max[src] : y3min[src];
  outp[gid] = fmaxf((v - mean) * rs * g3[o] + be3[o], 0.0f);
}

extern "C" void kernel_launch(void* const* d_in, const int* in_sizes, int n_in,
                              void* d_out, int out_size, void* d_ws, size_t ws_size,
                              hipStream_t stream) {
  const float* xyz  = (const float*)d_in[0];
  const float* feats = (const float*)d_in[1];
  const float* W1 = (const float*)d_in[2];
  const float* b1 = (const float*)d_in[3];
  const float* g1 = (const float*)d_in[4];
  const float* be1 = (const float*)d_in[5];
  const float* W2 = (const float*)d_in[6];
  const float* b2 = (const float*)d_in[7];
  const float* g2 = (const float*)d_in[8];
  const float* be2 = (const float*)d_in[9];
  const float* W3 = (const float*)d_in[10];
  const float* b3 = (const float*)d_in[11];
  const float* g3 = (const float*)d_in[12];
  const float* be3 = (const float*)d_in[13];

  float* out = (float*)d_out;
  float* centers = out;                  // B*M*3
  float* outp = out + (size_t)B_ * M_ * 3;

  float* wsf = (float*)d_ws;
  int* idx = (int*)wsf;
  float* y3max = wsf + WS_Y3MAX;
  float* y3min = wsf + WS_Y3MIN;
  float* stats = wsf + WS_STATS;

  hipMemsetAsync(stats, 0, 512 * sizeof(float), stream);
  k_knn_bf<<<16384, 256, 0, stream>>>(xyz, centers, idx);
  n_stats1<<<2048, 256, 0, stream>>>(xyz, feats, idx, W1, b1, stats);
  n_stats2<<<2048, 256, 0, stream>>>(xyz, feats, idx, W1, b1, g1, be1, W2, b2, stats);
  n_stats3<<<2048, 256, 0, stream>>>(xyz, feats, idx, W1, b1, g1, be1, W2, b2, g2, be2,
                                     W3, b3, stats, y3max, y3min);
  k_out<<<8192, 256, 0, stream>>>(y3max, y3min, stats, g3, be3, outp);
}

// Round 7
// 1192.467 us; speedup vs baseline: 10.2540x; 10.2540x over previous
//
#include <hip/hip_runtime.h>

#define B_ 8
#define P_ 8192
#define M_ 2048
#define K_ 32
#define CIN_ 64
#define C3_ 128
#define BM_ (B_*M_)
#define NTOT_f 524288.0f
#define BN_EPS_ 1e-5f
#define POOLCAP 128

// workspace layout (in floats): idx | featsT | y3max | y3min | stats
#define WS_FT    (BM_*K_)                    // 524288 ints first
#define WS_Y3MAX (WS_FT + B_*P_*CIN_)
#define WS_Y3MIN (WS_Y3MAX + BM_*C3_)
#define WS_STATS (WS_Y3MIN + BM_*C3_)        // 512 floats

__device__ inline int center_index(int m) {
  const double step = (double)(P_ - 1) / (double)(M_ - 1);
  return (m == M_ - 1) ? (P_ - 1) : (int)((double)m * step);
}

__device__ inline unsigned short f2bf(float f) {
  unsigned int u = __float_as_uint(f);
  unsigned int r = (u + 0x7fffu + ((u >> 16) & 1u)) >> 16;
  return (unsigned short)r;
}
__device__ inline float bf2f(unsigned short s) {
  return __uint_as_float(((unsigned int)s) << 16);
}

// strict (non-contracted) f32 sum of squares: (x2+y2)+z2  [golden assoc, R6]
__device__ inline float sq3(float a, float b, float c) {
  return __fadd_rn(__fadd_rn(__fmul_rn(a, a), __fmul_rn(b, b)), __fmul_rn(c, c));
}

// ---------------- transpose feats (B,C,P) -> featsT (B,P,C) ----------------
__global__ __launch_bounds__(256) void k_transpose(const float* __restrict__ feats,
                                                   float* __restrict__ ftT) {
  __shared__ float tile[64][65];
  int b = blockIdx.x >> 7;
  int p0 = (blockIdx.x & 127) << 6;
  const float* fb = feats + (size_t)b * CIN_ * P_;
  float* ob = ftT + (size_t)b * P_ * CIN_;
  for (int i = threadIdx.x; i < 64 * 64; i += 256) {
    int c = i >> 6, pp = i & 63;
    tile[c][pp] = fb[c * P_ + p0 + pp];
  }
  __syncthreads();
  for (int i = threadIdx.x; i < 64 * 64; i += 256) {
    int pp = i >> 6, c = i & 63;
    ob[(size_t)(p0 + pp) * CIN_ + c] = tile[c][pp];
  }
}

// ---------------- KNN: streaming pool + bitonic compact, golden-f32 d2 -----
// d2 = (ccs + pp) - 2*dot; dot = fma(cz,pz, fma(cy,py, cx*px)); squares strict.
// Machinery brute-force-validated R4-R6. Stream order => new idx > pooled idx,
// so "d2 < kth" is the exact lexicographic (d2, idx) filter.
__device__ inline void cmpx_elem(float& v, int& ix, int i, int size, int d) {
  float pv = __shfl_xor(v, d);
  int pi = __shfl_xor(ix, d);
  bool up = ((i & size) == 0);
  bool lower = ((i & d) == 0);
  bool less = (v < pv) || (v == pv && ix < pi);
  bool keep = (lower == up) ? less : !less;
  if (!keep) { v = pv; ix = pi; }
}

__device__ void pool_compact(float* pv_, int* pi_, int& pc, float& kth, int lane) {
  __threadfence_block();
  float v0 = (lane < pc) ? pv_[lane] : __builtin_inff();
  int   i0 = (lane < pc) ? pi_[lane] : 0x7fffffff;
  float v1 = (lane + 64 < pc) ? pv_[lane + 64] : __builtin_inff();
  int   i1 = (lane + 64 < pc) ? pi_[lane + 64] : 0x7fffffff;
  for (int size = 2; size <= 128; size <<= 1) {
    if (size == 128) {
      bool less = (v0 < v1) || (v0 == v1 && i0 < i1);
      if (!less) { float tv = v0; v0 = v1; v1 = tv; int ti = i0; i0 = i1; i1 = ti; }
    }
    for (int d = (size == 128 ? 32 : (size >> 1)); d >= 1; d >>= 1) {
      cmpx_elem(v0, i0, lane, size, d);
      cmpx_elem(v1, i1, lane + 64, size, d);
    }
  }
  if (lane < 32) { pv_[lane] = v0; pi_[lane] = i0; }
  __threadfence_block();
  pc = 32;
  kth = __shfl(v0, 31);
}

__global__ __launch_bounds__(256) void k_knn(const float* __restrict__ xyz,
                                             float* __restrict__ centers_out,
                                             int* __restrict__ knn_idx) {
  __shared__ float pvals[4][4][POOLCAP];
  __shared__ int   pidxs[4][4][POOLCAP];
  const int w = threadIdx.x >> 6, lane = threadIdx.x & 63;
  const int gw = blockIdx.x * 4 + w;
  const int cid0 = gw * 4;
  const int b = cid0 >> 11;
  const float* xyzb = xyz + (size_t)b * P_ * 3;

  float cx[4], cy[4], cz[4], ccs[4], kth[4];
  int pc[4];
  #pragma unroll
  for (int cc = 0; cc < 4; cc++) {
    int m = (cid0 + cc) & (M_ - 1);
    int ci = center_index(m);
    cx[cc] = xyzb[ci * 3 + 0];
    cy[cc] = xyzb[ci * 3 + 1];
    cz[cc] = xyzb[ci * 3 + 2];
    ccs[cc] = sq3(cx[cc], cy[cc], cz[cc]);
    kth[cc] = __builtin_inff();
    pc[cc] = 0;
  }
  if (lane < 12) {
    int cc = lane / 3, c = lane % 3;
    int m = (cid0 + cc) & (M_ - 1);
    int ci = center_index(m);
    centers_out[(size_t)(cid0 + cc) * 3 + c] = xyzb[ci * 3 + c];
  }

  for (int bi = 0; bi < P_ / 64; bi++) {
    int p = bi * 64 + lane;
    float px = xyzb[p * 3 + 0], py = xyzb[p * 3 + 1], pz = xyzb[p * 3 + 2];
    float pp = sq3(px, py, pz);
    #pragma unroll
    for (int cc = 0; cc < 4; cc++) {
      float dot = __fmul_rn(cx[cc], px);
      dot = __builtin_fmaf(cy[cc], py, dot);
      dot = __builtin_fmaf(cz[cc], pz, dot);
      float d2 = __fsub_rn(__fadd_rn(ccs[cc], pp), __fmul_rn(2.0f, dot));
      bool pass = d2 < kth[cc];
      unsigned long long mask = __ballot(pass);
      if (mask) {
        int cnt = __popcll(mask);
        if (pc[cc] + cnt > POOLCAP)
          pool_compact(&pvals[w][cc][0], &pidxs[w][cc][0], pc[cc], kth[cc], lane);
        int rank = __popcll(mask & ((1ull << lane) - 1ull));
        if (pass) {
          pvals[w][cc][pc[cc] + rank] = d2;
          pidxs[w][cc][pc[cc] + rank] = p;
        }
        pc[cc] += cnt;
      }
    }
  }
  #pragma unroll
  for (int cc = 0; cc < 4; cc++) {
    pool_compact(&pvals[w][cc][0], &pidxs[w][cc][0], pc[cc], kth[cc], lane);
    if (lane < K_) knn_idx[(size_t)(cid0 + cc) * K_ + lane] = pidxs[w][cc][lane];
  }
}

// ---------------- gather + GEMM helpers ----------------
__device__ inline void gather_x(const float* __restrict__ xyz, const float* __restrict__ ftT,
                                const int* __restrict__ knn_idx, int cid, int lane,
                                float (*xb)[68]) {
  const int b = cid >> 11;
  const int m = cid & (M_ - 1);
  const int ci = center_index(m);
  const float* xyzb = xyz + (size_t)b * P_ * 3;
  const float ctr0 = xyzb[ci * 3 + 0], ctr1 = xyzb[ci * 3 + 1], ctr2 = xyzb[ci * 3 + 2];
  const int k = lane >> 1;
  const int half = lane & 1;
  const int p = knn_idx[(size_t)cid * K_ + k];
  const float* frow = ftT + ((size_t)b * P_ + p) * CIN_;
  const int cbase = half * 34;
  #pragma unroll
  for (int j = 0; j < 34; j++) {
    const int c = cbase + j;
    float v;
    if (c < 3) {
      float pv = xyzb[p * 3 + c];
      float cv = (c == 0) ? ctr0 : ((c == 1) ? ctr1 : ctr2);
      v = pv - cv;
    } else if (c < 67) {
      v = frow[c - 3];
    } else {
      v = 0.0f;
    }
    xb[k][c] = v;
  }
}

template<int NJ, int NC4, int WCOLS>
__device__ inline void gemm_bf16(const float (*xb)[68], const unsigned short* wl,
                                 int kg, int og, float (&acc)[4][NJ]) {
  for (int c4 = 0; c4 < NC4; c4++) {
    float4 xa[4];
    #pragma unroll
    for (int kk = 0; kk < 4; kk++)
      xa[kk] = *(const float4*)(&xb[kg * 4 + kk][c4 * 4]);
    #pragma unroll
    for (int j = 0; j < NJ; j++) {
      ushort4 wv = *(const ushort4*)(wl + (og + j * 8) * WCOLS + c4 * 4);
      float w0 = bf2f(wv.x), w1 = bf2f(wv.y), w2 = bf2f(wv.z), w3 = bf2f(wv.w);
      #pragma unroll
      for (int kk = 0; kk < 4; kk++) {
        float t = acc[kk][j];
        t = fmaf(xa[kk].x, w0, t);
        t = fmaf(xa[kk].y, w1, t);
        t = fmaf(xa[kk].z, w2, t);
        t = fmaf(xa[kk].w, w3, t);
        acc[kk][j] = t;
      }
    }
  }
}

__device__ inline float red_kg_sum(float v) {
  v += __shfl_xor(v, 8);
  v += __shfl_xor(v, 16);
  v += __shfl_xor(v, 32);
  return v;
}
__device__ inline float red_kg_max(float v) {
  v = fmaxf(v, __shfl_xor(v, 8));
  v = fmaxf(v, __shfl_xor(v, 16));
  v = fmaxf(v, __shfl_xor(v, 32));
  return v;
}
__device__ inline float red_kg_min(float v) {
  v = fminf(v, __shfl_xor(v, 8));
  v = fminf(v, __shfl_xor(v, 16));
  v = fminf(v, __shfl_xor(v, 32));
  return v;
}

// ---------------- stats1: y1 sums ----------------
__global__ __launch_bounds__(128) void k_stats1(const float* __restrict__ xyz,
                                                const float* __restrict__ ftT,
                                                const int* __restrict__ knn_idx,
                                                const float* __restrict__ W1,
                                                const float* __restrict__ b1,
                                                float* __restrict__ stats) {
  __shared__ __align__(16) unsigned short ws1[64 * 68];
  __shared__ __align__(16) float xb[2][32][68];
  __shared__ float s1buf[2][64], q1buf[2][64];
  const int t = threadIdx.x, w = t >> 6, lane = t & 63;
  const int kg = lane >> 3, og = lane & 7;

  for (int i = t; i < 64 * 68; i += 128) {
    int o = i / 68, c = i - o * 68;
    ws1[i] = f2bf(c < 67 ? W1[o * 67 + c] : 0.0f);
  }
  __syncthreads();

  float bj[8], sacc[8], qacc[8];
  #pragma unroll
  for (int j = 0; j < 8; j++) { bj[j] = b1[og + j * 8]; sacc[j] = 0.f; qacc[j] = 0.f; }

  const int cidbase = blockIdx.x * 16 + w * 8;
  for (int n = 0; n < 8; n++) {
    int cid = cidbase + n;
    gather_x(xyz, ftT, knn_idx, cid, lane, xb[w]);
    __syncthreads();
    float acc[4][8];
    #pragma unroll
    for (int kk = 0; kk < 4; kk++)
      #pragma unroll
      for (int j = 0; j < 8; j++) acc[kk][j] = 0.f;
    gemm_bf16<8, 17, 68>(xb[w], ws1, kg, og, acc);
    #pragma unroll
    for (int j = 0; j < 8; j++)
      #pragma unroll
      for (int kk = 0; kk < 4; kk++) {
        float y = acc[kk][j] + bj[j];
        sacc[j] += y;
        qacc[j] = fmaf(y, y, qacc[j]);
      }
    __syncthreads();
  }
  #pragma unroll
  for (int j = 0; j < 8; j++) { sacc[j] = red_kg_sum(sacc[j]); qacc[j] = red_kg_sum(qacc[j]); }
  if (kg == 0) {
    #pragma unroll
    for (int j = 0; j < 8; j++) { s1buf[w][og + j * 8] = sacc[j]; q1buf[w][og + j * 8] = qacc[j]; }
  }
  __syncthreads();
  if (t < 64) {
    atomicAdd(&stats[t], s1buf[0][t] + s1buf[1][t]);
    atomicAdd(&stats[64 + t], q1buf[0][t] + q1buf[1][t]);
  }
}

// ---------------- stats2: recompute y1, bn1+relu, y2 sums ----------------
__global__ __launch_bounds__(128) void k_stats2(const float* __restrict__ xyz,
                                                const float* __restrict__ ftT,
                                                const int* __restrict__ knn_idx,
                                                const float* __restrict__ W1,
                                                const float* __restrict__ b1,
                                                const float* __restrict__ g1,
                                                const float* __restrict__ be1,
                                                const float* __restrict__ W2,
                                                const float* __restrict__ b2,
                                                float* __restrict__ stats) {
  __shared__ __align__(16) unsigned short ws1[64 * 68];
  __shared__ __align__(16) unsigned short ws2[64 * 64];
  __shared__ __align__(16) float xb[2][32][68];
  __shared__ float sc1[64], sh1[64];
  __shared__ float s2buf[2][64], q2buf[2][64];
  const int t = threadIdx.x, w = t >> 6, lane = t & 63;
  const int kg = lane >> 3, og = lane & 7;

  if (t < 64) {
    float mean = stats[t] * (1.0f / NTOT_f);
    float var = stats[64 + t] * (1.0f / NTOT_f) - mean * mean;
    float rs = rsqrtf(var + BN_EPS_);
    float sc = g1[t] * rs;
    sc1[t] = sc;
    sh1[t] = be1[t] - mean * sc;
  }
  for (int i = t; i < 64 * 68; i += 128) {
    int o = i / 68, c = i - o * 68;
    ws1[i] = f2bf(c < 67 ? W1[o * 67 + c] : 0.0f);
  }
  for (int i = t; i < 64 * 64; i += 128) ws2[i] = f2bf(W2[i]);
  __syncthreads();

  float b1j[8], b2j[8], scl[8], shl[8], sacc[8], qacc[8];
  #pragma unroll
  for (int j = 0; j < 8; j++) {
    b1j[j] = b1[og + j * 8]; b2j[j] = b2[og + j * 8];
    scl[j] = sc1[og + j * 8]; shl[j] = sh1[og + j * 8];
    sacc[j] = 0.f; qacc[j] = 0.f;
  }

  const int cidbase = blockIdx.x * 16 + w * 8;
  for (int n = 0; n < 8; n++) {
    int cid = cidbase + n;
    gather_x(xyz, ftT, knn_idx, cid, lane, xb[w]);
    __syncthreads();
    float acc[4][8];
    #pragma unroll
    for (int kk = 0; kk < 4; kk++)
      #pragma unroll
      for (int j = 0; j < 8; j++) acc[kk][j] = 0.f;
    gemm_bf16<8, 17, 68>(xb[w], ws1, kg, og, acc);
    #pragma unroll
    for (int j = 0; j < 8; j++)
      #pragma unroll
      for (int kk = 0; kk < 4; kk++) {
        float y = acc[kk][j] + b1j[j];
        float h = fmaxf(fmaf(y, scl[j], shl[j]), 0.0f);
        xb[w][kg * 4 + kk][og + j * 8] = h;
      }
    __syncthreads();
    float acc2[4][8];
    #pragma unroll
    for (int kk = 0; kk < 4; kk++)
      #pragma unroll
      for (int j = 0; j < 8; j++) acc2[kk][j] = 0.f;
    gemm_bf16<8, 16, 64>(xb[w], ws2, kg, og, acc2);
    #pragma unroll
    for (int j = 0; j < 8; j++)
      #pragma unroll
      for (int kk = 0; kk < 4; kk++) {
        float y = acc2[kk][j] + b2j[j];
        sacc[j] += y;
        qacc[j] = fmaf(y, y, qacc[j]);
      }
    __syncthreads();
  }
  #pragma unroll
  for (int j = 0; j < 8; j++) { sacc[j] = red_kg_sum(sacc[j]); qacc[j] = red_kg_sum(qacc[j]); }
  if (kg == 0) {
    #pragma unroll
    for (int j = 0; j < 8; j++) { s2buf[w][og + j * 8] = sacc[j]; q2buf[w][og + j * 8] = qacc[j]; }
  }
  __syncthreads();
  if (t < 64) {
    atomicAdd(&stats[128 + t], s2buf[0][t] + s2buf[1][t]);
    atomicAdd(&stats[192 + t], q2buf[0][t] + q2buf[1][t]);
  }
}

// ---------------- stats3: full recompute, y3 sums + max/min over k ----------------
__global__ __launch_bounds__(128) void k_stats3(const float* __restrict__ xyz,
                                                const float* __restrict__ ftT,
                                                const int* __restrict__ knn_idx,
                                                const float* __restrict__ W1,
                                                const float* __restrict__ b1,
                                                const float* __restrict__ g1,
                                                const float* __restrict__ be1,
                                                const float* __restrict__ W2,
                                                const float* __restrict__ b2,
                                                const float* __restrict__ g2,
                                                const float* __restrict__ be2,
                                                const float* __restrict__ W3,
                                                const float* __restrict__ b3,
                                                float* __restrict__ stats,
                                                float* __restrict__ y3max,
                                                float* __restrict__ y3min) {
  __shared__ __align__(16) unsigned short ws1[64 * 68];
  __shared__ __align__(16) unsigned short ws2[64 * 64];
  __shared__ __align__(16) unsigned short ws3[128 * 64];
  __shared__ __align__(16) float xb[2][32][68];
  __shared__ float sc1[64], sh1[64], sc2[64], sh2[64];
  __shared__ float s3buf[2][128], q3buf[2][128];
  const int t = threadIdx.x, w = t >> 6, lane = t & 63;
  const int kg = lane >> 3, og = lane & 7;

  if (t < 64) {
    float mean = stats[t] * (1.0f / NTOT_f);
    float var = stats[64 + t] * (1.0f / NTOT_f) - mean * mean;
    float rs = rsqrtf(var + BN_EPS_);
    float sc = g1[t] * rs;
    sc1[t] = sc;
    sh1[t] = be1[t] - mean * sc;
    float mean2 = stats[128 + t] * (1.0f / NTOT_f);
    float var2 = stats[192 + t] * (1.0f / NTOT_f) - mean2 * mean2;
    float rs2 = rsqrtf(var2 + BN_EPS_);
    float scb = g2[t] * rs2;
    sc2[t] = scb;
    sh2[t] = be2[t] - mean2 * scb;
  }
  for (int i = t; i < 64 * 68; i += 128) {
    int o = i / 68, c = i - o * 68;
    ws1[i] = f2bf(c < 67 ? W1[o * 67 + c] : 0.0f);
  }
  for (int i = t; i < 64 * 64; i += 128) ws2[i] = f2bf(W2[i]);
  for (int i = t; i < 128 * 64; i += 128) ws3[i] = f2bf(W3[i]);
  __syncthreads();

  float b1j[8], b2j[8], sc1l[8], sh1l[8], sc2l[8], sh2l[8];
  #pragma unroll
  for (int j = 0; j < 8; j++) {
    b1j[j] = b1[og + j * 8]; b2j[j] = b2[og + j * 8];
    sc1l[j] = sc1[og + j * 8]; sh1l[j] = sh1[og + j * 8];
    sc2l[j] = sc2[og + j * 8]; sh2l[j] = sh2[og + j * 8];
  }
  float b3j[16], sacc[16], qacc[16];
  #pragma unroll
  for (int j = 0; j < 16; j++) { b3j[j] = b3[og + j * 8]; sacc[j] = 0.f; qacc[j] = 0.f; }

  const int cidbase = blockIdx.x * 16 + w * 8;
  for (int n = 0; n < 8; n++) {
    int cid = cidbase + n;
    gather_x(xyz, ftT, knn_idx, cid, lane, xb[w]);
    __syncthreads();
    float acc[4][8];
    #pragma unroll
    for (int kk = 0; kk < 4; kk++)
      #pragma unroll
      for (int j = 0; j < 8; j++) acc[kk][j] = 0.f;
    gemm_bf16<8, 17, 68>(xb[w], ws1, kg, og, acc);
    #pragma unroll
    for (int j = 0; j < 8; j++)
      #pragma unroll
      for (int kk = 0; kk < 4; kk++) {
        float y = acc[kk][j] + b1j[j];
        xb[w][kg * 4 + kk][og + j * 8] = fmaxf(fmaf(y, sc1l[j], sh1l[j]), 0.0f);
      }
    __syncthreads();
    #pragma unroll
    for (int kk = 0; kk < 4; kk++)
      #pragma unroll
      for (int j = 0; j < 8; j++) acc[kk][j] = 0.f;
    gemm_bf16<8, 16, 64>(xb[w], ws2, kg, og, acc);
    __syncthreads();
    #pragma unroll
    for (int j = 0; j < 8; j++)
      #pragma unroll
      for (int kk = 0; kk < 4; kk++) {
        float y = acc[kk][j] + b2j[j];
        xb[w][kg * 4 + kk][og + j * 8] = fmaxf(fmaf(y, sc2l[j], sh2l[j]), 0.0f);
      }
    __syncthreads();
    float acc3[4][16];
    #pragma unroll
    for (int kk = 0; kk < 4; kk++)
      #pragma unroll
      for (int j = 0; j < 16; j++) acc3[kk][j] = 0.f;
    gemm_bf16<16, 16, 64>(xb[w], ws3, kg, og, acc3);
    #pragma unroll
    for (int j = 0; j < 16; j++) {
      float vmax = -__builtin_inff(), vmin = __builtin_inff();
      #pragma unroll
      for (int kk = 0; kk < 4; kk++) {
        float y = acc3[kk][j] + b3j[j];
        sacc[j] += y;
        qacc[j] = fmaf(y, y, qacc[j]);
        vmax = fmaxf(vmax, y);
        vmin = fminf(vmin, y);
      }
      vmax = red_kg_max(vmax);
      vmin = red_kg_min(vmin);
      if (kg == 0) {
        y3max[(size_t)cid * C3_ + og + j * 8] = vmax;
        y3min[(size_t)cid * C3_ + og + j * 8] = vmin;
      }
    }
    __syncthreads();
  }
  #pragma unroll
  for (int j = 0; j < 16; j++) { sacc[j] = red_kg_sum(sacc[j]); qacc[j] = red_kg_sum(qacc[j]); }
  if (kg == 0) {
    #pragma unroll
    for (int j = 0; j < 16; j++) { s3buf[w][og + j * 8] = sacc[j]; q3buf[w][og + j * 8] = qacc[j]; }
  }
  __syncthreads();
  if (t < 128) {
    atomicAdd(&stats[256 + t], s3buf[0][t] + s3buf[1][t]);
    atomicAdd(&stats[384 + t], q3buf[0][t] + q3buf[1][t]);
  }
}

// ---------------- final output ----------------
__global__ __launch_bounds__(256) void k_out(const float* __restrict__ y3max,
                                             const float* __restrict__ y3min,
                                             const float* __restrict__ stats,
                                             const float* __restrict__ g3,
                                             const float* __restrict__ be3,
                                             float* __restrict__ outp) {
  __shared__ float sc[128], sh[128];
  const int t = threadIdx.x;
  if (t < 128) {
    float mean = stats[256 + t] * (1.0f / NTOT_f);
    float var = stats[384 + t] * (1.0f / NTOT_f) - mean * mean;
    float rs = rsqrtf(var + BN_EPS_);
    float s = g3[t] * rs;
    sc[t] = s;
    sh[t] = be3[t] - mean * s;
  }
  __syncthreads();
  int gid = blockIdx.x * 256 + t;
  int m = gid & (M_ - 1);
  int o = (gid >> 11) & 127;
  int b = gid >> 18;
  float s = sc[o], h = sh[o];
  size_t src = ((size_t)(b * M_ + m)) * C3_ + o;
  float v = (s >= 0.0f) ? y3max[src] : y3min[src];
  outp[gid] = fmaxf(fmaf(v, s, h), 0.0f);
}

extern "C" void kernel_launch(void* const* d_in, const int* in_sizes, int n_in,
                              void* d_out, int out_size, void* d_ws, size_t ws_size,
                              hipStream_t stream) {
  const float* xyz  = (const float*)d_in[0];
  const float* feats = (const float*)d_in[1];
  const float* W1 = (const float*)d_in[2];
  const float* b1 = (const float*)d_in[3];
  const float* g1 = (const float*)d_in[4];
  const float* be1 = (const float*)d_in[5];
  const float* W2 = (const float*)d_in[6];
  const float* b2 = (const float*)d_in[7];
  const float* g2 = (const float*)d_in[8];
  const float* be2 = (const float*)d_in[9];
  const float* W3 = (const float*)d_in[10];
  const float* b3 = (const float*)d_in[11];
  const float* g3 = (const float*)d_in[12];
  const float* be3 = (const float*)d_in[13];

  float* out = (float*)d_out;
  float* centers = out;                  // B*M*3
  float* outp = out + (size_t)B_ * M_ * 3;

  float* wsf = (float*)d_ws;
  int* idx = (int*)wsf;
  float* ftT = wsf + WS_FT;
  float* y3max = wsf + WS_Y3MAX;
  float* y3min = wsf + WS_Y3MIN;
  float* stats = wsf + WS_STATS;

  hipMemsetAsync(stats, 0, 512 * sizeof(float), stream);
  k_transpose<<<1024, 256, 0, stream>>>(feats, ftT);
  k_knn<<<1024, 256, 0, stream>>>(xyz, centers, idx);
  k_stats1<<<1024, 128, 0, stream>>>(xyz, ftT, idx, W1, b1, stats);
  k_stats2<<<1024, 128, 0, stream>>>(xyz, ftT, idx, W1, b1, g1, be1, W2, b2, stats);
  k_stats3<<<1024, 128, 0, stream>>>(xyz, ftT, idx, W1, b1, g1, be1, W2, b2, g2, be2,
                                     W3, b3, stats, y3max, y3min);
  k_out<<<8192, 256, 0, stream>>>(y3max, y3min, stats, g3, be3, outp);
}

// Round 8
// 1175.366 us; speedup vs baseline: 10.4032x; 1.0145x over previous
//
#include <hip/hip_runtime.h>

#define B_ 8
#define P_ 8192
#define M_ 2048
#define K_ 32
#define CIN_ 64
#define C3_ 128
#define BM_ (B_*M_)
#define NTOT_f 524288.0f
#define BN_EPS_ 1e-5f
#define POOLCAP 128
#define XSTR 70   // xb row stride in floats: (24kg+6kk+4c4)%32 -> 2-way (free)

// workspace layout (in floats): idx | featsT | y3max | y3min | stats
#define WS_FT    (BM_*K_)                    // 524288 ints first
#define WS_Y3MAX (WS_FT + B_*P_*CIN_)
#define WS_Y3MIN (WS_Y3MAX + BM_*C3_)
#define WS_STATS (WS_Y3MIN + BM_*C3_)        // 512 floats

__device__ inline int center_index(int m) {
  const double step = (double)(P_ - 1) / (double)(M_ - 1);
  return (m == M_ - 1) ? (P_ - 1) : (int)((double)m * step);
}

__device__ inline unsigned short f2bf(float f) {
  unsigned int u = __float_as_uint(f);
  unsigned int r = (u + 0x7fffu + ((u >> 16) & 1u)) >> 16;
  return (unsigned short)r;
}
__device__ inline float bf2f(unsigned short s) {
  return __uint_as_float(((unsigned int)s) << 16);
}

// strict (non-contracted) f32 sum of squares: (x2+y2)+z2  [golden assoc, R6]
__device__ inline float sq3(float a, float b, float c) {
  return __fadd_rn(__fadd_rn(__fmul_rn(a, a), __fmul_rn(b, b)), __fmul_rn(c, c));
}

// ---------------- transpose feats (B,C,P) -> featsT (B,P,C) ----------------
__global__ __launch_bounds__(256) void k_transpose(const float* __restrict__ feats,
                                                   float* __restrict__ ftT) {
  __shared__ float tile[64][65];
  int b = blockIdx.x >> 7;
  int p0 = (blockIdx.x & 127) << 6;
  const float* fb = feats + (size_t)b * CIN_ * P_;
  float* ob = ftT + (size_t)b * P_ * CIN_;
  for (int i = threadIdx.x; i < 64 * 64; i += 256) {
    int c = i >> 6, pp = i & 63;
    tile[c][pp] = fb[c * P_ + p0 + pp];
  }
  __syncthreads();
  for (int i = threadIdx.x; i < 64 * 64; i += 256) {
    int pp = i >> 6, c = i & 63;
    ob[(size_t)(p0 + pp) * CIN_ + c] = tile[c][pp];
  }
}

// ---------------- KNN: streaming pool + bitonic compact, golden-f32 d2 -----
__device__ inline void cmpx_elem(float& v, int& ix, int i, int size, int d) {
  float pv = __shfl_xor(v, d);
  int pi = __shfl_xor(ix, d);
  bool up = ((i & size) == 0);
  bool lower = ((i & d) == 0);
  bool less = (v < pv) || (v == pv && ix < pi);
  bool keep = (lower == up) ? less : !less;
  if (!keep) { v = pv; ix = pi; }
}

__device__ void pool_compact(float* pv_, int* pi_, int& pc, float& kth, int lane) {
  __threadfence_block();
  float v0 = (lane < pc) ? pv_[lane] : __builtin_inff();
  int   i0 = (lane < pc) ? pi_[lane] : 0x7fffffff;
  float v1 = (lane + 64 < pc) ? pv_[lane + 64] : __builtin_inff();
  int   i1 = (lane + 64 < pc) ? pi_[lane + 64] : 0x7fffffff;
  for (int size = 2; size <= 128; size <<= 1) {
    if (size == 128) {
      bool less = (v0 < v1) || (v0 == v1 && i0 < i1);
      if (!less) { float tv = v0; v0 = v1; v1 = tv; int ti = i0; i0 = i1; i1 = ti; }
    }
    for (int d = (size == 128 ? 32 : (size >> 1)); d >= 1; d >>= 1) {
      cmpx_elem(v0, i0, lane, size, d);
      cmpx_elem(v1, i1, lane + 64, size, d);
    }
  }
  if (lane < 32) { pv_[lane] = v0; pi_[lane] = i0; }
  __threadfence_block();
  pc = 32;
  kth = __shfl(v0, 31);
}

__global__ __launch_bounds__(256) void k_knn(const float* __restrict__ xyz,
                                             float* __restrict__ centers_out,
                                             int* __restrict__ knn_idx) {
  __shared__ float pvals[4][4][POOLCAP];
  __shared__ int   pidxs[4][4][POOLCAP];
  const int w = threadIdx.x >> 6, lane = threadIdx.x & 63;
  const int gw = blockIdx.x * 4 + w;
  const int cid0 = gw * 4;
  const int b = cid0 >> 11;
  const float* xyzb = xyz + (size_t)b * P_ * 3;

  float cx[4], cy[4], cz[4], ccs[4], kth[4];
  int pc[4];
  #pragma unroll
  for (int cc = 0; cc < 4; cc++) {
    int m = (cid0 + cc) & (M_ - 1);
    int ci = center_index(m);
    cx[cc] = xyzb[ci * 3 + 0];
    cy[cc] = xyzb[ci * 3 + 1];
    cz[cc] = xyzb[ci * 3 + 2];
    ccs[cc] = sq3(cx[cc], cy[cc], cz[cc]);
    kth[cc] = __builtin_inff();
    pc[cc] = 0;
  }
  if (lane < 12) {
    int cc = lane / 3, c = lane % 3;
    int m = (cid0 + cc) & (M_ - 1);
    int ci = center_index(m);
    centers_out[(size_t)(cid0 + cc) * 3 + c] = xyzb[ci * 3 + c];
  }

  for (int bi = 0; bi < P_ / 64; bi++) {
    int p = bi * 64 + lane;
    float px = xyzb[p * 3 + 0], py = xyzb[p * 3 + 1], pz = xyzb[p * 3 + 2];
    float pp = sq3(px, py, pz);
    #pragma unroll
    for (int cc = 0; cc < 4; cc++) {
      float dot = __fmul_rn(cx[cc], px);
      dot = __builtin_fmaf(cy[cc], py, dot);
      dot = __builtin_fmaf(cz[cc], pz, dot);
      float d2 = __fsub_rn(__fadd_rn(ccs[cc], pp), __fmul_rn(2.0f, dot));
      bool pass = d2 < kth[cc];
      unsigned long long mask = __ballot(pass);
      if (mask) {
        int cnt = __popcll(mask);
        if (pc[cc] + cnt > POOLCAP)
          pool_compact(&pvals[w][cc][0], &pidxs[w][cc][0], pc[cc], kth[cc], lane);
        int rank = __popcll(mask & ((1ull << lane) - 1ull));
        if (pass) {
          pvals[w][cc][pc[cc] + rank] = d2;
          pidxs[w][cc][pc[cc] + rank] = p;
        }
        pc[cc] += cnt;
      }
    }
  }
  #pragma unroll
  for (int cc = 0; cc < 4; cc++) {
    pool_compact(&pvals[w][cc][0], &pidxs[w][cc][0], pc[cc], kth[cc], lane);
    if (lane < K_) knn_idx[(size_t)(cid0 + cc) * K_ + lane] = pidxs[w][cc][lane];
  }
}

// ---------------- gather + GEMM helpers ----------------
__device__ inline void gather_x(const float* __restrict__ xyz, const float* __restrict__ ftT,
                                const int* __restrict__ knn_idx, int cid, int lane,
                                float (*xb)[XSTR]) {
  const int b = cid >> 11;
  const int m = cid & (M_ - 1);
  const int ci = center_index(m);
  const float* xyzb = xyz + (size_t)b * P_ * 3;
  const float ctr0 = xyzb[ci * 3 + 0], ctr1 = xyzb[ci * 3 + 1], ctr2 = xyzb[ci * 3 + 2];
  const int k = lane >> 1;
  const int half = lane & 1;
  const int p = knn_idx[(size_t)cid * K_ + k];
  const float* frow = ftT + ((size_t)b * P_ + p) * CIN_;
  const int cbase = half * 34;
  #pragma unroll
  for (int j = 0; j < 34; j++) {
    const int c = cbase + j;
    float v;
    if (c < 3) {
      float pv = xyzb[p * 3 + c];
      float cv = (c == 0) ? ctr0 : ((c == 1) ? ctr1 : ctr2);
      v = pv - cv;
    } else if (c < 67) {
      v = frow[c - 3];
    } else {
      v = 0.0f;
    }
    xb[k][c] = v;
  }
}

template<int NJ, int NC4, int WCOLS>
__device__ inline void gemm_bf16(const float (*xb)[XSTR], const unsigned short* wl,
                                 int kg, int og, float (&acc)[4][NJ]) {
  for (int c4 = 0; c4 < NC4; c4++) {
    float2 xa0[4], xa1[4];
    #pragma unroll
    for (int kk = 0; kk < 4; kk++) {
      xa0[kk] = *(const float2*)(&xb[kg * 4 + kk][c4 * 4]);
      xa1[kk] = *(const float2*)(&xb[kg * 4 + kk][c4 * 4 + 2]);
    }
    #pragma unroll
    for (int j = 0; j < NJ; j++) {
      ushort4 wv = *(const ushort4*)(wl + (og + j * 8) * WCOLS + c4 * 4);
      float w0 = bf2f(wv.x), w1 = bf2f(wv.y), w2 = bf2f(wv.z), w3 = bf2f(wv.w);
      #pragma unroll
      for (int kk = 0; kk < 4; kk++) {
        float t = acc[kk][j];
        t = fmaf(xa0[kk].x, w0, t);
        t = fmaf(xa0[kk].y, w1, t);
        t = fmaf(xa1[kk].x, w2, t);
        t = fmaf(xa1[kk].y, w3, t);
        acc[kk][j] = t;
      }
    }
  }
}

__device__ inline float red_kg_sum(float v) {
  v += __shfl_xor(v, 8);
  v += __shfl_xor(v, 16);
  v += __shfl_xor(v, 32);
  return v;
}
__device__ inline float red_kg_max(float v) {
  v = fmaxf(v, __shfl_xor(v, 8));
  v = fmaxf(v, __shfl_xor(v, 16));
  v = fmaxf(v, __shfl_xor(v, 32));
  return v;
}
__device__ inline float red_kg_min(float v) {
  v = fminf(v, __shfl_xor(v, 8));
  v = fminf(v, __shfl_xor(v, 16));
  v = fminf(v, __shfl_xor(v, 32));
  return v;
}

// ---------------- stats1: y1 sums ----------------
__global__ __launch_bounds__(256) void k_stats1(const float* __restrict__ xyz,
                                                const float* __restrict__ ftT,
                                                const int* __restrict__ knn_idx,
                                                const float* __restrict__ W1,
                                                const float* __restrict__ b1,
                                                float* __restrict__ stats) {
  __shared__ __align__(16) unsigned short ws1[64 * 68];
  __shared__ __align__(16) float xb[4][32][XSTR];
  __shared__ float s1buf[4][64], q1buf[4][64];
  const int t = threadIdx.x, w = t >> 6, lane = t & 63;
  const int kg = lane >> 3, og = lane & 7;

  for (int i = t; i < 64 * 68; i += 256) {
    int o = i / 68, c = i - o * 68;
    ws1[i] = f2bf(c < 67 ? W1[o * 67 + c] : 0.0f);
  }
  __syncthreads();

  float bj[8], sacc[8], qacc[8];
  #pragma unroll
  for (int j = 0; j < 8; j++) { bj[j] = b1[og + j * 8]; sacc[j] = 0.f; qacc[j] = 0.f; }

  const int cidbase = blockIdx.x * 32 + w * 8;
  for (int n = 0; n < 8; n++) {
    int cid = cidbase + n;
    gather_x(xyz, ftT, knn_idx, cid, lane, xb[w]);
    __syncthreads();
    float acc[4][8];
    #pragma unroll
    for (int kk = 0; kk < 4; kk++)
      #pragma unroll
      for (int j = 0; j < 8; j++) acc[kk][j] = 0.f;
    gemm_bf16<8, 17, 68>(xb[w], ws1, kg, og, acc);
    #pragma unroll
    for (int j = 0; j < 8; j++)
      #pragma unroll
      for (int kk = 0; kk < 4; kk++) {
        float y = acc[kk][j] + bj[j];
        sacc[j] += y;
        qacc[j] = fmaf(y, y, qacc[j]);
      }
    __syncthreads();
  }
  #pragma unroll
  for (int j = 0; j < 8; j++) { sacc[j] = red_kg_sum(sacc[j]); qacc[j] = red_kg_sum(qacc[j]); }
  if (kg == 0) {
    #pragma unroll
    for (int j = 0; j < 8; j++) { s1buf[w][og + j * 8] = sacc[j]; q1buf[w][og + j * 8] = qacc[j]; }
  }
  __syncthreads();
  if (t < 64) {
    atomicAdd(&stats[t], (s1buf[0][t] + s1buf[1][t]) + (s1buf[2][t] + s1buf[3][t]));
    atomicAdd(&stats[64 + t], (q1buf[0][t] + q1buf[1][t]) + (q1buf[2][t] + q1buf[3][t]));
  }
}

// ---------------- stats2: recompute y1, bn1+relu, y2 sums ----------------
__global__ __launch_bounds__(256) void k_stats2(const float* __restrict__ xyz,
                                                const float* __restrict__ ftT,
                                                const int* __restrict__ knn_idx,
                                                const float* __restrict__ W1,
                                                const float* __restrict__ b1,
                                                const float* __restrict__ g1,
                                                const float* __restrict__ be1,
                                                const float* __restrict__ W2,
                                                const float* __restrict__ b2,
                                                float* __restrict__ stats) {
  __shared__ __align__(16) unsigned short ws1[64 * 68];
  __shared__ __align__(16) unsigned short ws2[64 * 64];
  __shared__ __align__(16) float xb[4][32][XSTR];
  __shared__ float sc1[64], sh1[64];
  __shared__ float s2buf[4][64], q2buf[4][64];
  const int t = threadIdx.x, w = t >> 6, lane = t & 63;
  const int kg = lane >> 3, og = lane & 7;

  if (t < 64) {
    float mean = stats[t] * (1.0f / NTOT_f);
    float var = stats[64 + t] * (1.0f / NTOT_f) - mean * mean;
    float rs = rsqrtf(var + BN_EPS_);
    float sc = g1[t] * rs;
    sc1[t] = sc;
    sh1[t] = be1[t] - mean * sc;
  }
  for (int i = t; i < 64 * 68; i += 256) {
    int o = i / 68, c = i - o * 68;
    ws1[i] = f2bf(c < 67 ? W1[o * 67 + c] : 0.0f);
  }
  for (int i = t; i < 64 * 64; i += 256) ws2[i] = f2bf(W2[i]);
  __syncthreads();

  float b1j[8], b2j[8], scl[8], shl[8], sacc[8], qacc[8];
  #pragma unroll
  for (int j = 0; j < 8; j++) {
    b1j[j] = b1[og + j * 8]; b2j[j] = b2[og + j * 8];
    scl[j] = sc1[og + j * 8]; shl[j] = sh1[og + j * 8];
    sacc[j] = 0.f; qacc[j] = 0.f;
  }

  const int cidbase = blockIdx.x * 32 + w * 8;
  for (int n = 0; n < 8; n++) {
    int cid = cidbase + n;
    gather_x(xyz, ftT, knn_idx, cid, lane, xb[w]);
    __syncthreads();
    float acc[4][8];
    #pragma unroll
    for (int kk = 0; kk < 4; kk++)
      #pragma unroll
      for (int j = 0; j < 8; j++) acc[kk][j] = 0.f;
    gemm_bf16<8, 17, 68>(xb[w], ws1, kg, og, acc);
    #pragma unroll
    for (int j = 0; j < 8; j++)
      #pragma unroll
      for (int kk = 0; kk < 4; kk++) {
        float y = acc[kk][j] + b1j[j];
        float h = fmaxf(fmaf(y, scl[j], shl[j]), 0.0f);
        xb[w][kg * 4 + kk][og + j * 8] = h;
      }
    __syncthreads();
    float acc2[4][8];
    #pragma unroll
    for (int kk = 0; kk < 4; kk++)
      #pragma unroll
      for (int j = 0; j < 8; j++) acc2[kk][j] = 0.f;
    gemm_bf16<8, 16, 64>(xb[w], ws2, kg, og, acc2);
    #pragma unroll
    for (int j = 0; j < 8; j++)
      #pragma unroll
      for (int kk = 0; kk < 4; kk++) {
        float y = acc2[kk][j] + b2j[j];
        sacc[j] += y;
        qacc[j] = fmaf(y, y, qacc[j]);
      }
    __syncthreads();
  }
  #pragma unroll
  for (int j = 0; j < 8; j++) { sacc[j] = red_kg_sum(sacc[j]); qacc[j] = red_kg_sum(qacc[j]); }
  if (kg == 0) {
    #pragma unroll
    for (int j = 0; j < 8; j++) { s2buf[w][og + j * 8] = sacc[j]; q2buf[w][og + j * 8] = qacc[j]; }
  }
  __syncthreads();
  if (t < 64) {
    atomicAdd(&stats[128 + t], (s2buf[0][t] + s2buf[1][t]) + (s2buf[2][t] + s2buf[3][t]));
    atomicAdd(&stats[192 + t], (q2buf[0][t] + q2buf[1][t]) + (q2buf[2][t] + q2buf[3][t]));
  }
}

// ---------------- stats3: full recompute, y3 sums + max/min over k ----------------
__global__ __launch_bounds__(256) void k_stats3(const float* __restrict__ xyz,
                                                const float* __restrict__ ftT,
                                                const int* __restrict__ knn_idx,
                                                const float* __restrict__ W1,
                                                const float* __restrict__ b1,
                                                const float* __restrict__ g1,
                                                const float* __restrict__ be1,
                                                const float* __restrict__ W2,
                                                const float* __restrict__ b2,
                                                const float* __restrict__ g2,
                                                const float* __restrict__ be2,
                                                const float* __restrict__ W3,
                                                const float* __restrict__ b3,
                                                float* __restrict__ stats,
                                                float* __restrict__ y3max,
                                                float* __restrict__ y3min) {
  __shared__ __align__(16) unsigned short ws1[64 * 68];
  __shared__ __align__(16) unsigned short ws2[64 * 64];
  __shared__ __align__(16) unsigned short ws3[128 * 64];
  __shared__ __align__(16) float xb[4][32][XSTR];
  __shared__ float sc1[64], sh1[64], sc2[64], sh2[64];
  __shared__ float s3buf[4][128], q3buf[4][128];
  const int t = threadIdx.x, w = t >> 6, lane = t & 63;
  const int kg = lane >> 3, og = lane & 7;

  if (t < 64) {
    float mean = stats[t] * (1.0f / NTOT_f);
    float var = stats[64 + t] * (1.0f / NTOT_f) - mean * mean;
    float rs = rsqrtf(var + BN_EPS_);
    float sc = g1[t] * rs;
    sc1[t] = sc;
    sh1[t] = be1[t] - mean * sc;
    float mean2 = stats[128 + t] * (1.0f / NTOT_f);
    float var2 = stats[192 + t] * (1.0f / NTOT_f) - mean2 * mean2;
    float rs2 = rsqrtf(var2 + BN_EPS_);
    float scb = g2[t] * rs2;
    sc2[t] = scb;
    sh2[t] = be2[t] - mean2 * scb;
  }
  for (int i = t; i < 64 * 68; i += 256) {
    int o = i / 68, c = i - o * 68;
    ws1[i] = f2bf(c < 67 ? W1[o * 67 + c] : 0.0f);
  }
  for (int i = t; i < 64 * 64; i += 256) ws2[i] = f2bf(W2[i]);
  for (int i = t; i < 128 * 64; i += 256) ws3[i] = f2bf(W3[i]);
  __syncthreads();

  float b1j[8], b2j[8], sc1l[8], sh1l[8], sc2l[8], sh2l[8];
  #pragma unroll
  for (int j = 0; j < 8; j++) {
    b1j[j] = b1[og + j * 8]; b2j[j] = b2[og + j * 8];
    sc1l[j] = sc1[og + j * 8]; sh1l[j] = sh1[og + j * 8];
    sc2l[j] = sc2[og + j * 8]; sh2l[j] = sh2[og + j * 8];
  }
  float b3j[16], sacc[16], qacc[16];
  #pragma unroll
  for (int j = 0; j < 16; j++) { b3j[j] = b3[og + j * 8]; sacc[j] = 0.f; qacc[j] = 0.f; }

  const int cidbase = blockIdx.x * 32 + w * 8;
  for (int n = 0; n < 8; n++) {
    int cid = cidbase + n;
    gather_x(xyz, ftT, knn_idx, cid, lane, xb[w]);
    __syncthreads();
    float acc[4][8];
    #pragma unroll
    for (int kk = 0; kk < 4; kk++)
      #pragma unroll
      for (int j = 0; j < 8; j++) acc[kk][j] = 0.f;
    gemm_bf16<8, 17, 68>(xb[w], ws1, kg, og, acc);
    #pragma unroll
    for (int j = 0; j < 8; j++)
      #pragma unroll
      for (int kk = 0; kk < 4; kk++) {
        float y = acc[kk][j] + b1j[j];
        xb[w][kg * 4 + kk][og + j * 8] = fmaxf(fmaf(y, sc1l[j], sh1l[j]), 0.0f);
      }
    __syncthreads();
    #pragma unroll
    for (int kk = 0; kk < 4; kk++)
      #pragma unroll
      for (int j = 0; j < 8; j++) acc[kk][j] = 0.f;
    gemm_bf16<8, 16, 64>(xb[w], ws2, kg, og, acc);
    __syncthreads();
    #pragma unroll
    for (int j = 0; j < 8; j++)
      #pragma unroll
      for (int kk = 0; kk < 4; kk++) {
        float y = acc[kk][j] + b2j[j];
        xb[w][kg * 4 + kk][og + j * 8] = fmaxf(fmaf(y, sc2l[j], sh2l[j]), 0.0f);
      }
    __syncthreads();
    float acc3[4][16];
    #pragma unroll
    for (int kk = 0; kk < 4; kk++)
      #pragma unroll
      for (int j = 0; j < 16; j++) acc3[kk][j] = 0.f;
    gemm_bf16<16, 16, 64>(xb[w], ws3, kg, og, acc3);
    #pragma unroll
    for (int j = 0; j < 16; j++) {
      float vmax = -__builtin_inff(), vmin = __builtin_inff();
      #pragma unroll
      for (int kk = 0; kk < 4; kk++) {
        float y = acc3[kk][j] + b3j[j];
        sacc[j] += y;
        qacc[j] = fmaf(y, y, qacc[j]);
        vmax = fmaxf(vmax, y);
        vmin = fminf(vmin, y);
      }
      vmax = red_kg_max(vmax);
      vmin = red_kg_min(vmin);
      if (kg == 0) {
        y3max[(size_t)cid * C3_ + og + j * 8] = vmax;
        y3min[(size_t)cid * C3_ + og + j * 8] = vmin;
      }
    }
    __syncthreads();
  }
  #pragma unroll
  for (int j = 0; j < 16; j++) { sacc[j] = red_kg_sum(sacc[j]); qacc[j] = red_kg_sum(qacc[j]); }
  if (kg == 0) {
    #pragma unroll
    for (int j = 0; j < 16; j++) { s3buf[w][og + j * 8] = sacc[j]; q3buf[w][og + j * 8] = qacc[j]; }
  }
  __syncthreads();
  if (t < 128) {
    atomicAdd(&stats[256 + t], (s3buf[0][t] + s3buf[1][t]) + (s3buf[2][t] + s3buf[3][t]));
    atomicAdd(&stats[384 + t], (q3buf[0][t] + q3buf[1][t]) + (q3buf[2][t] + q3buf[3][t]));
  }
}

// ---------------- final output ----------------
__global__ __launch_bounds__(256) void k_out(const float* __restrict__ y3max,
                                             const float* __restrict__ y3min,
                                             const float* __restrict__ stats,
                                             const float* __restrict__ g3,
                                             const float* __restrict__ be3,
                                             float* __restrict__ outp) {
  __shared__ float sc[128], sh[128];
  const int t = threadIdx.x;
  if (t < 128) {
    float mean = stats[256 + t] * (1.0f / NTOT_f);
    float var = stats[384 + t] * (1.0f / NTOT_f) - mean * mean;
    float rs = rsqrtf(var + BN_EPS_);
    float s = g3[t] * rs;
    sc[t] = s;
    sh[t] = be3[t] - mean * s;
  }
  __syncthreads();
  int gid = blockIdx.x * 256 + t;
  int m = gid & (M_ - 1);
  int o = (gid >> 11) & 127;
  int b = gid >> 18;
  float s = sc[o], h = sh[o];
  size_t src = ((size_t)(b * M_ + m)) * C3_ + o;
  float v = (s >= 0.0f) ? y3max[src] : y3min[src];
  outp[gid] = fmaxf(fmaf(v, s, h), 0.0f);
}

extern "C" void kernel_launch(void* const* d_in, const int* in_sizes, int n_in,
                              void* d_out, int out_size, void* d_ws, size_t ws_size,
                              hipStream_t stream) {
  const float* xyz  = (const float*)d_in[0];
  const float* feats = (const float*)d_in[1];
  const float* W1 = (const float*)d_in[2];
  const float* b1 = (const float*)d_in[3];
  const float* g1 = (const float*)d_in[4];
  const float* be1 = (const float*)d_in[5];
  const float* W2 = (const float*)d_in[6];
  const float* b2 = (const float*)d_in[7];
  const float* g2 = (const float*)d_in[8];
  const float* be2 = (const float*)d_in[9];
  const float* W3 = (const float*)d_in[10];
  const float* b3 = (const float*)d_in[11];
  const float* g3 = (const float*)d_in[12];
  const float* be3 = (const float*)d_in[13];

  float* out = (float*)d_out;
  float* centers = out;                  // B*M*3
  float* outp = out + (size_t)B_ * M_ * 3;

  float* wsf = (float*)d_ws;
  int* idx = (int*)wsf;
  float* ftT = wsf + WS_FT;
  float* y3max = wsf + WS_Y3MAX;
  float* y3min = wsf + WS_Y3MIN;
  float* stats = wsf + WS_STATS;

  hipMemsetAsync(stats, 0, 512 * sizeof(float), stream);
  k_transpose<<<1024, 256, 0, stream>>>(feats, ftT);
  k_knn<<<1024, 256, 0, stream>>>(xyz, centers, idx);
  k_stats1<<<512, 256, 0, stream>>>(xyz, ftT, idx, W1, b1, stats);
  k_stats2<<<512, 256, 0, stream>>>(xyz, ftT, idx, W1, b1, g1, be1, W2, b2, stats);
  k_stats3<<<512, 256, 0, stream>>>(xyz, ftT, idx, W1, b1, g1, be1, W2, b2, g2, be2,
                                    W3, b3, stats, y3max, y3min);
  k_out<<<8192, 256, 0, stream>>>(y3max, y3min, stats, g3, be3, outp);
}

// Round 9
// 431.025 us; speedup vs baseline: 28.3685x; 2.7269x over previous
//
#include <hip/hip_runtime.h>

#define B_ 8
#define P_ 8192
#define M_ 2048
#define K_ 32
#define CIN_ 64
#define C3_ 128
#define BM_ (B_*M_)
#define NTOT_f 524288.0f
#define BN_EPS_ 1e-5f
#define POOLCAP 128
#define XW_STR 112   // ushort stride of x/h rows in LDS (224 B, uniform b128 spread)
#define W3_STR 72    // ushort stride of W3 rows in LDS (144 B; 64 would be 8-way conflict)

typedef __attribute__((ext_vector_type(8))) short bf16x8;
typedef __attribute__((ext_vector_type(4))) float f32x4;

// workspace layout (in floats): idx | featsT | y3max | y3min | stats
#define WS_FT    (BM_*K_)
#define WS_Y3MAX (WS_FT + B_*P_*CIN_)
#define WS_Y3MIN (WS_Y3MAX + BM_*C3_)
#define WS_STATS (WS_Y3MIN + BM_*C3_)        // 512 floats

__device__ inline int center_index(int m) {
  const double step = (double)(P_ - 1) / (double)(M_ - 1);
  return (m == M_ - 1) ? (P_ - 1) : (int)((double)m * step);
}

__device__ inline unsigned short f2bf(float f) {
  unsigned int u = __float_as_uint(f);
  unsigned int r = (u + 0x7fffu + ((u >> 16) & 1u)) >> 16;
  return (unsigned short)r;
}

// strict (non-contracted) f32 sum of squares: (x2+y2)+z2  [golden assoc, R6]
__device__ inline float sq3(float a, float b, float c) {
  return __fadd_rn(__fadd_rn(__fmul_rn(a, a), __fmul_rn(b, b)), __fmul_rn(c, c));
}

// ---------------- transpose feats (B,C,P) -> featsT (B,P,C) ----------------
__global__ __launch_bounds__(256) void k_transpose(const float* __restrict__ feats,
                                                   float* __restrict__ ftT) {
  __shared__ float tile[64][65];
  int b = blockIdx.x >> 7;
  int p0 = (blockIdx.x & 127) << 6;
  const float* fb = feats + (size_t)b * CIN_ * P_;
  float* ob = ftT + (size_t)b * P_ * CIN_;
  for (int i = threadIdx.x; i < 64 * 64; i += 256) {
    int c = i >> 6, pp = i & 63;
    tile[c][pp] = fb[c * P_ + p0 + pp];
  }
  __syncthreads();
  for (int i = threadIdx.x; i < 64 * 64; i += 256) {
    int pp = i >> 6, c = i & 63;
    ob[(size_t)(p0 + pp) * CIN_ + c] = tile[c][pp];
  }
}

// ---------------- KNN: streaming pool + bitonic compact, golden-f32 d2 -----
__device__ inline void cmpx_elem(float& v, int& ix, int i, int size, int d) {
  float pv = __shfl_xor(v, d);
  int pi = __shfl_xor(ix, d);
  bool up = ((i & size) == 0);
  bool lower = ((i & d) == 0);
  bool less = (v < pv) || (v == pv && ix < pi);
  bool keep = (lower == up) ? less : !less;
  if (!keep) { v = pv; ix = pi; }
}

__device__ void pool_compact(float* pv_, int* pi_, int& pc, float& kth, int lane) {
  __threadfence_block();
  float v0 = (lane < pc) ? pv_[lane] : __builtin_inff();
  int   i0 = (lane < pc) ? pi_[lane] : 0x7fffffff;
  float v1 = (lane + 64 < pc) ? pv_[lane + 64] : __builtin_inff();
  int   i1 = (lane + 64 < pc) ? pi_[lane + 64] : 0x7fffffff;
  for (int size = 2; size <= 128; size <<= 1) {
    if (size == 128) {
      bool less = (v0 < v1) || (v0 == v1 && i0 < i1);
      if (!less) { float tv = v0; v0 = v1; v1 = tv; int ti = i0; i0 = i1; i1 = ti; }
    }
    for (int d = (size == 128 ? 32 : (size >> 1)); d >= 1; d >>= 1) {
      cmpx_elem(v0, i0, lane, size, d);
      cmpx_elem(v1, i1, lane + 64, size, d);
    }
  }
  if (lane < 32) { pv_[lane] = v0; pi_[lane] = i0; }
  __threadfence_block();
  pc = 32;
  kth = __shfl(v0, 31);
}

__global__ __launch_bounds__(256) void k_knn(const float* __restrict__ xyz,
                                             float* __restrict__ centers_out,
                                             int* __restrict__ knn_idx) {
  __shared__ float pvals[4][4][POOLCAP];
  __shared__ int   pidxs[4][4][POOLCAP];
  const int w = threadIdx.x >> 6, lane = threadIdx.x & 63;
  const int gw = blockIdx.x * 4 + w;
  const int cid0 = gw * 4;
  const int b = cid0 >> 11;
  const float* xyzb = xyz + (size_t)b * P_ * 3;

  float cx[4], cy[4], cz[4], ccs[4], kth[4];
  int pc[4];
  #pragma unroll
  for (int cc = 0; cc < 4; cc++) {
    int m = (cid0 + cc) & (M_ - 1);
    int ci = center_index(m);
    cx[cc] = xyzb[ci * 3 + 0];
    cy[cc] = xyzb[ci * 3 + 1];
    cz[cc] = xyzb[ci * 3 + 2];
    ccs[cc] = sq3(cx[cc], cy[cc], cz[cc]);
    kth[cc] = __builtin_inff();
    pc[cc] = 0;
  }
  if (lane < 12) {
    int cc = lane / 3, c = lane % 3;
    int m = (cid0 + cc) & (M_ - 1);
    int ci = center_index(m);
    centers_out[(size_t)(cid0 + cc) * 3 + c] = xyzb[ci * 3 + c];
  }

  for (int bi = 0; bi < P_ / 64; bi++) {
    int p = bi * 64 + lane;
    float px = xyzb[p * 3 + 0], py = xyzb[p * 3 + 1], pz = xyzb[p * 3 + 2];
    float pp = sq3(px, py, pz);
    #pragma unroll
    for (int cc = 0; cc < 4; cc++) {
      float dot = __fmul_rn(cx[cc], px);
      dot = __builtin_fmaf(cy[cc], py, dot);
      dot = __builtin_fmaf(cz[cc], pz, dot);
      float d2 = __fsub_rn(__fadd_rn(ccs[cc], pp), __fmul_rn(2.0f, dot));
      bool pass = d2 < kth[cc];
      unsigned long long mask = __ballot(pass);
      if (mask) {
        int cnt = __popcll(mask);
        if (pc[cc] + cnt > POOLCAP)
          pool_compact(&pvals[w][cc][0], &pidxs[w][cc][0], pc[cc], kth[cc], lane);
        int rank = __popcll(mask & ((1ull << lane) - 1ull));
        if (pass) {
          pvals[w][cc][pc[cc] + rank] = d2;
          pidxs[w][cc][pc[cc] + rank] = p;
        }
        pc[cc] += cnt;
      }
    }
  }
  #pragma unroll
  for (int cc = 0; cc < 4; cc++) {
    pool_compact(&pvals[w][cc][0], &pidxs[w][cc][0], pc[cc], kth[cc], lane);
    if (lane < K_) knn_idx[(size_t)(cid0 + cc) * K_ + lane] = pidxs[w][cc][lane];
  }
}

// ---------------- MFMA helpers ----------------
// Channel permutation: x cols [0..63]=feats, [64..66]=local_xyz, [67..95]=0.
// gather: wave-private LDS tile xw[32][XW_STR] bf16, 2 lanes per row.
__device__ inline void gather_mfma(const float* __restrict__ xyz,
                                   const float* __restrict__ ftT,
                                   const int* __restrict__ knn,
                                   int cid, int lane,
                                   unsigned short* __restrict__ xq) {
  const int b = cid >> 11;
  const int m = cid & (M_ - 1);
  const int ci = center_index(m);
  const float* xyzb = xyz + (size_t)b * P_ * 3;
  const int r = lane >> 1, hf = lane & 1;
  const int p = knn[(size_t)cid * K_ + r];
  const float* frow = ftT + ((size_t)b * P_ + p) * CIN_ + hf * 32;
  unsigned short* row = xq + r * XW_STR;
  #pragma unroll
  for (int i = 0; i < 8; i++) {
    float4 v = *(const float4*)(frow + i * 4);
    ushort4 u = make_ushort4(f2bf(v.x), f2bf(v.y), f2bf(v.z), f2bf(v.w));
    *(ushort4*)(row + hf * 32 + i * 4) = u;
  }
  if (hf == 0) {
    float dx = xyzb[p * 3 + 0] - xyzb[ci * 3 + 0];
    float dy = xyzb[p * 3 + 1] - xyzb[ci * 3 + 1];
    float dz = xyzb[p * 3 + 2] - xyzb[ci * 3 + 2];
    ushort4 u = make_ushort4(f2bf(dx), f2bf(dy), f2bf(dz), 0);
    *(ushort4*)(row + 64) = u;
  } else {
    ushort4 z = make_ushort4(0, 0, 0, 0);
    #pragma unroll
    for (int i = 0; i < 7; i++) *(ushort4*)(row + 68 + i * 4) = z;
  }
}

// W1 fragments (permuted cols) into registers: w1f[nt][s], nt<4 (16 oc each), s<3 (K=32 each)
__device__ inline void load_w1_frags(const float* __restrict__ W1, int lane, bf16x8 (&w1f)[4][3]) {
  const int o16 = lane & 15, q = lane >> 4;
  #pragma unroll
  for (int nt = 0; nt < 4; nt++) {
    const float* wr = W1 + (nt * 16 + o16) * 67;
    #pragma unroll
    for (int s = 0; s < 3; s++) {
      bf16x8 f;
      #pragma unroll
      for (int j = 0; j < 8; j++) {
        int c = s * 32 + q * 8 + j;
        float v = (c < 64) ? wr[c + 3] : ((c < 67) ? wr[c - 64] : 0.0f);
        f[j] = (short)f2bf(v);
      }
      w1f[nt][s] = f;
    }
  }
}

__device__ inline void load_w2_frags(const float* __restrict__ W2, int lane, bf16x8 (&w2f)[4][2]) {
  const int o16 = lane & 15, q = lane >> 4;
  #pragma unroll
  for (int nt = 0; nt < 4; nt++) {
    const float* wr = W2 + (nt * 16 + o16) * 64;
    #pragma unroll
    for (int s = 0; s < 2; s++) {
      bf16x8 f;
      #pragma unroll
      for (int j = 0; j < 8; j++) f[j] = (short)f2bf(wr[s * 32 + q * 8 + j]);
      w2f[nt][s] = f;
    }
  }
}

__device__ inline bf16x8 lds_afrag(const unsigned short* __restrict__ xq, int mt, int s, int lane) {
  return *(const bf16x8*)(xq + (mt * 16 + (lane & 15)) * XW_STR + s * 32 + (lane >> 4) * 8);
}

// ---------------- pass 1: G1 -> stats(y1) ----------------
__global__ __launch_bounds__(256, 3) void k_mf1(const float* __restrict__ xyz,
                                                const float* __restrict__ ftT,
                                                const int* __restrict__ knn,
                                                const float* __restrict__ W1,
                                                const float* __restrict__ b1,
                                                float* __restrict__ stats) {
  __shared__ __align__(16) unsigned short xw[4][32 * XW_STR];
  __shared__ float sld[128];
  const int t = threadIdx.x, w = t >> 6, lane = t & 63, o16 = lane & 15;
  if (t < 128) sld[t] = 0.0f;

  bf16x8 w1f[4][3];
  load_w1_frags(W1, lane, w1f);
  float b1l[4], sacc[4], qacc[4];
  #pragma unroll
  for (int nt = 0; nt < 4; nt++) { b1l[nt] = b1[nt * 16 + o16]; sacc[nt] = 0.f; qacc[nt] = 0.f; }
  __syncthreads();

  unsigned short* xq = &xw[w][0];
  const int cid0 = blockIdx.x * 32 + w * 8;
  for (int n = 0; n < 8; n++) {
    gather_mfma(xyz, ftT, knn, cid0 + n, lane, xq);
    f32x4 acc[2][4];
    #pragma unroll
    for (int mt = 0; mt < 2; mt++)
      #pragma unroll
      for (int nt = 0; nt < 4; nt++) acc[mt][nt] = (f32x4){0.f, 0.f, 0.f, 0.f};
    #pragma unroll
    for (int s = 0; s < 3; s++) {
      bf16x8 a0 = lds_afrag(xq, 0, s, lane);
      bf16x8 a1 = lds_afrag(xq, 1, s, lane);
      #pragma unroll
      for (int nt = 0; nt < 4; nt++) {
        acc[0][nt] = __builtin_amdgcn_mfma_f32_16x16x32_bf16(a0, w1f[nt][s], acc[0][nt], 0, 0, 0);
        acc[1][nt] = __builtin_amdgcn_mfma_f32_16x16x32_bf16(a1, w1f[nt][s], acc[1][nt], 0, 0, 0);
      }
    }
    #pragma unroll
    for (int nt = 0; nt < 4; nt++)
      #pragma unroll
      for (int mt = 0; mt < 2; mt++)
        #pragma unroll
        for (int rr = 0; rr < 4; rr++) {
          float y = acc[mt][nt][rr] + b1l[nt];
          sacc[nt] += y;
          qacc[nt] = fmaf(y, y, qacc[nt]);
        }
  }
  #pragma unroll
  for (int nt = 0; nt < 4; nt++) {
    float s = sacc[nt]; s += __shfl_xor(s, 16); s += __shfl_xor(s, 32);
    float qq = qacc[nt]; qq += __shfl_xor(qq, 16); qq += __shfl_xor(qq, 32);
    if (lane < 16) { atomicAdd(&sld[nt * 16 + lane], s); atomicAdd(&sld[64 + nt * 16 + lane], qq); }
  }
  __syncthreads();
  if (t < 64) { atomicAdd(&stats[t], sld[t]); atomicAdd(&stats[64 + t], sld[64 + t]); }
}

// ---------------- pass 2: G1 -> bn1 -> G2 -> stats(y2) ----------------
__global__ __launch_bounds__(256, 2) void k_mf2(const float* __restrict__ xyz,
                                                const float* __restrict__ ftT,
                                                const int* __restrict__ knn,
                                                const float* __restrict__ W1,
                                                const float* __restrict__ b1,
                                                const float* __restrict__ g1,
                                                const float* __restrict__ be1,
                                                const float* __restrict__ W2,
                                                const float* __restrict__ b2,
                                                float* __restrict__ stats) {
  __shared__ __align__(16) unsigned short xw[4][32 * XW_STR];
  __shared__ float sld[128];
  const int t = threadIdx.x, w = t >> 6, lane = t & 63, o16 = lane & 15, q = lane >> 4;
  if (t < 128) sld[t] = 0.0f;

  bf16x8 w1f[4][3];
  bf16x8 w2f[4][2];
  load_w1_frags(W1, lane, w1f);
  load_w2_frags(W2, lane, w2f);
  float b1l[4], sc1l[4], sh1l[4], b2l[4], sacc[4], qacc[4];
  #pragma unroll
  for (int nt = 0; nt < 4; nt++) {
    int o = nt * 16 + o16;
    float mean = stats[o] * (1.0f / NTOT_f);
    float var = stats[64 + o] * (1.0f / NTOT_f) - mean * mean;
    float rs = rsqrtf(var + BN_EPS_);
    sc1l[nt] = g1[o] * rs;
    sh1l[nt] = be1[o] - mean * sc1l[nt];
    b1l[nt] = b1[o];
    b2l[nt] = b2[o];
    sacc[nt] = 0.f; qacc[nt] = 0.f;
  }
  __syncthreads();

  unsigned short* xq = &xw[w][0];
  const int cid0 = blockIdx.x * 32 + w * 8;
  for (int n = 0; n < 8; n++) {
    gather_mfma(xyz, ftT, knn, cid0 + n, lane, xq);
    f32x4 acc[2][4];
    #pragma unroll
    for (int mt = 0; mt < 2; mt++)
      #pragma unroll
      for (int nt = 0; nt < 4; nt++) acc[mt][nt] = (f32x4){0.f, 0.f, 0.f, 0.f};
    #pragma unroll
    for (int s = 0; s < 3; s++) {
      bf16x8 a0 = lds_afrag(xq, 0, s, lane);
      bf16x8 a1 = lds_afrag(xq, 1, s, lane);
      #pragma unroll
      for (int nt = 0; nt < 4; nt++) {
        acc[0][nt] = __builtin_amdgcn_mfma_f32_16x16x32_bf16(a0, w1f[nt][s], acc[0][nt], 0, 0, 0);
        acc[1][nt] = __builtin_amdgcn_mfma_f32_16x16x32_bf16(a1, w1f[nt][s], acc[1][nt], 0, 0, 0);
      }
    }
    // bn1+relu -> h1 (bf16) back into xw rows, cols 0..63
    #pragma unroll
    for (int nt = 0; nt < 4; nt++)
      #pragma unroll
      for (int mt = 0; mt < 2; mt++)
        #pragma unroll
        for (int rr = 0; rr < 4; rr++) {
          float y = acc[mt][nt][rr] + b1l[nt];
          float h = fmaxf(fmaf(y, sc1l[nt], sh1l[nt]), 0.0f);
          xq[(mt * 16 + q * 4 + rr) * XW_STR + nt * 16 + o16] = f2bf(h);
        }
    f32x4 acc2[2][4];
    #pragma unroll
    for (int mt = 0; mt < 2; mt++)
      #pragma unroll
      for (int nt = 0; nt < 4; nt++) acc2[mt][nt] = (f32x4){0.f, 0.f, 0.f, 0.f};
    #pragma unroll
    for (int s = 0; s < 2; s++) {
      bf16x8 a0 = lds_afrag(xq, 0, s, lane);
      bf16x8 a1 = lds_afrag(xq, 1, s, lane);
      #pragma unroll
      for (int nt = 0; nt < 4; nt++) {
        acc2[0][nt] = __builtin_amdgcn_mfma_f32_16x16x32_bf16(a0, w2f[nt][s], acc2[0][nt], 0, 0, 0);
        acc2[1][nt] = __builtin_amdgcn_mfma_f32_16x16x32_bf16(a1, w2f[nt][s], acc2[1][nt], 0, 0, 0);
      }
    }
    #pragma unroll
    for (int nt = 0; nt < 4; nt++)
      #pragma unroll
      for (int mt = 0; mt < 2; mt++)
        #pragma unroll
        for (int rr = 0; rr < 4; rr++) {
          float y = acc2[mt][nt][rr] + b2l[nt];
          sacc[nt] += y;
          qacc[nt] = fmaf(y, y, qacc[nt]);
        }
  }
  #pragma unroll
  for (int nt = 0; nt < 4; nt++) {
    float s = sacc[nt]; s += __shfl_xor(s, 16); s += __shfl_xor(s, 32);
    float qq = qacc[nt]; qq += __shfl_xor(qq, 16); qq += __shfl_xor(qq, 32);
    if (lane < 16) { atomicAdd(&sld[nt * 16 + lane], s); atomicAdd(&sld[64 + nt * 16 + lane], qq); }
  }
  __syncthreads();
  if (t < 64) { atomicAdd(&stats[128 + t], sld[t]); atomicAdd(&stats[192 + t], sld[64 + t]); }
}

// ---------------- pass 3: G1->bn1->G2->bn2->G3 -> stats(y3) + max/min ------
__global__ __launch_bounds__(256, 2) void k_mf3(const float* __restrict__ xyz,
                                                const float* __restrict__ ftT,
                                                const int* __restrict__ knn,
                                                const float* __restrict__ W1,
                                                const float* __restrict__ b1,
                                                const float* __restrict__ g1,
                                                const float* __restrict__ be1,
                                                const float* __restrict__ W2,
                                                const float* __restrict__ b2,
                                                const float* __restrict__ g2,
                                                const float* __restrict__ be2,
                                                const float* __restrict__ W3,
                                                const float* __restrict__ b3,
                                                float* __restrict__ stats,
                                                float* __restrict__ y3max,
                                                float* __restrict__ y3min) {
  __shared__ __align__(16) unsigned short xw[4][32 * XW_STR];
  __shared__ __align__(16) unsigned short ws3[128 * W3_STR];
  __shared__ float sld[256];
  const int t = threadIdx.x, w = t >> 6, lane = t & 63, o16 = lane & 15, q = lane >> 4;
  if (t < 256) sld[t] = 0.0f;
  for (int i = t; i < 128 * 64; i += 256) {
    int o = i >> 6, c = i & 63;
    ws3[o * W3_STR + c] = f2bf(W3[i]);
  }

  bf16x8 w1f[4][3];
  bf16x8 w2f[4][2];
  load_w1_frags(W1, lane, w1f);
  load_w2_frags(W2, lane, w2f);
  float b1l[4], sc1l[4], sh1l[4], b2l[4], sc2l[4], sh2l[4];
  #pragma unroll
  for (int nt = 0; nt < 4; nt++) {
    int o = nt * 16 + o16;
    float mean = stats[o] * (1.0f / NTOT_f);
    float var = stats[64 + o] * (1.0f / NTOT_f) - mean * mean;
    float rs = rsqrtf(var + BN_EPS_);
    sc1l[nt] = g1[o] * rs;
    sh1l[nt] = be1[o] - mean * sc1l[nt];
    b1l[nt] = b1[o];
    float mean2 = stats[128 + o] * (1.0f / NTOT_f);
    float var2 = stats[192 + o] * (1.0f / NTOT_f) - mean2 * mean2;
    float rs2 = rsqrtf(var2 + BN_EPS_);
    sc2l[nt] = g2[o] * rs2;
    sh2l[nt] = be2[o] - mean2 * sc2l[nt];
    b2l[nt] = b2[o];
  }
  float b3l[8], sacc[8], qacc[8];
  #pragma unroll
  for (int nt = 0; nt < 8; nt++) { b3l[nt] = b3[nt * 16 + o16]; sacc[nt] = 0.f; qacc[nt] = 0.f; }
  __syncthreads();

  unsigned short* xq = &xw[w][0];
  const int cid0 = blockIdx.x * 32 + w * 8;
  for (int n = 0; n < 8; n++) {
    const int cid = cid0 + n;
    gather_mfma(xyz, ftT, knn, cid, lane, xq);
    f32x4 acc[2][4];
    #pragma unroll
    for (int mt = 0; mt < 2; mt++)
      #pragma unroll
      for (int nt = 0; nt < 4; nt++) acc[mt][nt] = (f32x4){0.f, 0.f, 0.f, 0.f};
    #pragma unroll
    for (int s = 0; s < 3; s++) {
      bf16x8 a0 = lds_afrag(xq, 0, s, lane);
      bf16x8 a1 = lds_afrag(xq, 1, s, lane);
      #pragma unroll
      for (int nt = 0; nt < 4; nt++) {
        acc[0][nt] = __builtin_amdgcn_mfma_f32_16x16x32_bf16(a0, w1f[nt][s], acc[0][nt], 0, 0, 0);
        acc[1][nt] = __builtin_amdgcn_mfma_f32_16x16x32_bf16(a1, w1f[nt][s], acc[1][nt], 0, 0, 0);
      }
    }
    #pragma unroll
    for (int nt = 0; nt < 4; nt++)
      #pragma unroll
      for (int mt = 0; mt < 2; mt++)
        #pragma unroll
        for (int rr = 0; rr < 4; rr++) {
          float y = acc[mt][nt][rr] + b1l[nt];
          float h = fmaxf(fmaf(y, sc1l[nt], sh1l[nt]), 0.0f);
          xq[(mt * 16 + q * 4 + rr) * XW_STR + nt * 16 + o16] = f2bf(h);
        }
    #pragma unroll
    for (int mt = 0; mt < 2; mt++)
      #pragma unroll
      for (int nt = 0; nt < 4; nt++) acc[mt][nt] = (f32x4){0.f, 0.f, 0.f, 0.f};
    #pragma unroll
    for (int s = 0; s < 2; s++) {
      bf16x8 a0 = lds_afrag(xq, 0, s, lane);
      bf16x8 a1 = lds_afrag(xq, 1, s, lane);
      #pragma unroll
      for (int nt = 0; nt < 4; nt++) {
        acc[0][nt] = __builtin_amdgcn_mfma_f32_16x16x32_bf16(a0, w2f[nt][s], acc[0][nt], 0, 0, 0);
        acc[1][nt] = __builtin_amdgcn_mfma_f32_16x16x32_bf16(a1, w2f[nt][s], acc[1][nt], 0, 0, 0);
      }
    }
    #pragma unroll
    for (int nt = 0; nt < 4; nt++)
      #pragma unroll
      for (int mt = 0; mt < 2; mt++)
        #pragma unroll
        for (int rr = 0; rr < 4; rr++) {
          float y = acc[mt][nt][rr] + b2l[nt];
          float h = fmaxf(fmaf(y, sc2l[nt], sh2l[nt]), 0.0f);
          xq[(mt * 16 + q * 4 + rr) * XW_STR + nt * 16 + o16] = f2bf(h);
        }
    f32x4 acc3[2][8];
    #pragma unroll
    for (int mt = 0; mt < 2; mt++)
      #pragma unroll
      for (int nt = 0; nt < 8; nt++) acc3[mt][nt] = (f32x4){0.f, 0.f, 0.f, 0.f};
    #pragma unroll
    for (int s = 0; s < 2; s++) {
      bf16x8 a0 = lds_afrag(xq, 0, s, lane);
      bf16x8 a1 = lds_afrag(xq, 1, s, lane);
      #pragma unroll
      for (int nt = 0; nt < 8; nt++) {
        bf16x8 bf = *(const bf16x8*)(ws3 + (nt * 16 + o16) * W3_STR + s * 32 + q * 8);
        acc3[0][nt] = __builtin_amdgcn_mfma_f32_16x16x32_bf16(a0, bf, acc3[0][nt], 0, 0, 0);
        acc3[1][nt] = __builtin_amdgcn_mfma_f32_16x16x32_bf16(a1, bf, acc3[1][nt], 0, 0, 0);
      }
    }
    #pragma unroll
    for (int nt = 0; nt < 8; nt++) {
      float mx = -__builtin_inff(), mn = __builtin_inff();
      #pragma unroll
      for (int mt = 0; mt < 2; mt++)
        #pragma unroll
        for (int rr = 0; rr < 4; rr++) {
          float y = acc3[mt][nt][rr] + b3l[nt];
          sacc[nt] += y;
          qacc[nt] = fmaf(y, y, qacc[nt]);
          mx = fmaxf(mx, y);
          mn = fminf(mn, y);
        }
      mx = fmaxf(mx, __shfl_xor(mx, 16)); mx = fmaxf(mx, __shfl_xor(mx, 32));
      mn = fminf(mn, __shfl_xor(mn, 16)); mn = fminf(mn, __shfl_xor(mn, 32));
      if (lane < 16) {
        y3max[(size_t)cid * C3_ + nt * 16 + lane] = mx;
        y3min[(size_t)cid * C3_ + nt * 16 + lane] = mn;
      }
    }
  }
  #pragma unroll
  for (int nt = 0; nt < 8; nt++) {
    float s = sacc[nt]; s += __shfl_xor(s, 16); s += __shfl_xor(s, 32);
    float qq = qacc[nt]; qq += __shfl_xor(qq, 16); qq += __shfl_xor(qq, 32);
    if (lane < 16) { atomicAdd(&sld[nt * 16 + lane], s); atomicAdd(&sld[128 + nt * 16 + lane], qq); }
  }
  __syncthreads();
  if (t < 128) { atomicAdd(&stats[256 + t], sld[t]); atomicAdd(&stats[384 + t], sld[128 + t]); }
}

// ---------------- final output ----------------
__global__ __launch_bounds__(256) void k_out(const float* __restrict__ y3max,
                                             const float* __restrict__ y3min,
                                             const float* __restrict__ stats,
                                             const float* __restrict__ g3,
                                             const float* __restrict__ be3,
                                             float* __restrict__ outp) {
  __shared__ float sc[128], sh[128];
  const int t = threadIdx.x;
  if (t < 128) {
    float mean = stats[256 + t] * (1.0f / NTOT_f);
    float var = stats[384 + t] * (1.0f / NTOT_f) - mean * mean;
    float rs = rsqrtf(var + BN_EPS_);
    float s = g3[t] * rs;
    sc[t] = s;
    sh[t] = be3[t] - mean * s;
  }
  __syncthreads();
  int gid = blockIdx.x * 256 + t;
  int m = gid & (M_ - 1);
  int o = (gid >> 11) & 127;
  int b = gid >> 18;
  float s = sc[o], h = sh[o];
  size_t src = ((size_t)(b * M_ + m)) * C3_ + o;
  float v = (s >= 0.0f) ? y3max[src] : y3min[src];
  outp[gid] = fmaxf(fmaf(v, s, h), 0.0f);
}

extern "C" void kernel_launch(void* const* d_in, const int* in_sizes, int n_in,
                              void* d_out, int out_size, void* d_ws, size_t ws_size,
                              hipStream_t stream) {
  const float* xyz  = (const float*)d_in[0];
  const float* feats = (const float*)d_in[1];
  const float* W1 = (const float*)d_in[2];
  const float* b1 = (const float*)d_in[3];
  const float* g1 = (const float*)d_in[4];
  const float* be1 = (const float*)d_in[5];
  const float* W2 = (const float*)d_in[6];
  const float* b2 = (const float*)d_in[7];
  const float* g2 = (const float*)d_in[8];
  const float* be2 = (const float*)d_in[9];
  const float* W3 = (const float*)d_in[10];
  const float* b3 = (const float*)d_in[11];
  const float* g3 = (const float*)d_in[12];
  const float* be3 = (const float*)d_in[13];

  float* out = (float*)d_out;
  float* centers = out;                  // B*M*3
  float* outp = out + (size_t)B_ * M_ * 3;

  float* wsf = (float*)d_ws;
  int* idx = (int*)wsf;
  float* ftT = wsf + WS_FT;
  float* y3max = wsf + WS_Y3MAX;
  float* y3min = wsf + WS_Y3MIN;
  float* stats = wsf + WS_STATS;

  hipMemsetAsync(stats, 0, 512 * sizeof(float), stream);
  k_transpose<<<1024, 256, 0, stream>>>(feats, ftT);
  k_knn<<<1024, 256, 0, stream>>>(xyz, centers, idx);
  k_mf1<<<512, 256, 0, stream>>>(xyz, ftT, idx, W1, b1, stats);
  k_mf2<<<512, 256, 0, stream>>>(xyz, ftT, idx, W1, b1, g1, be1, W2, b2, stats);
  k_mf3<<<512, 256, 0, stream>>>(xyz, ftT, idx, W1, b1, g1, be1, W2, b2, g2, be2,
                                 W3, b3, stats, y3max, y3min);
  k_out<<<8192, 256, 0, stream>>>(y3max, y3min, stats, g3, be3, outp);
}